// Round 5
// baseline (160.482 us; speedup 1.0000x reference)
//
#include <hip/hip_runtime.h>
#include <math.h>

// SegmentGatingNetwork, MFMA path v6: non-draining K-loop barriers.
// vs v5: __syncthreads() in the K-loop replaced by {s_waitcnt lgkmcnt(0);
// sched_barrier(0); s_barrier} (8-phase-template pattern) so the x/B register
// prefetches stay in flight across barriers (hipcc's __syncthreads emits
// vmcnt(0) which was force-draining the prefetch every iteration = exposed
// HBM latency x32). x prefetch deepened to 3 slots; B loads issued BEFORE the
// x load so the rotate's wait is vmcnt(1), not vmcnt(0). Math identical (bit-exact).

#define DM 1024
#define DH 256
#define NE 64

// d_ws layout (bytes)
#define W1P_OFF 0                 // 3 planes * 131072 dwords
#define W1P_STRIDE 524288         // bytes per W1 plane
#define W2P_OFF 1572864           // 3 planes * 8192 dwords
#define W2P_STRIDE 32768

#define HSTR 276                  // h LDS row stride in dwords
#define AROW 80                   // bytes per token row in A staging (5*16: aligned, bank-spread)
#define APLANE 2560               // 32 tokens * AROW
#define ABUF 7680                 // 3 planes

typedef __attribute__((ext_vector_type(8))) short bf16x8;
typedef __attribute__((ext_vector_type(4))) float f32x4;

__device__ __forceinline__ unsigned fbits(float f) { return __float_as_uint(f); }
__device__ __forceinline__ float topf(unsigned u) { return __uint_as_float(u & 0xFFFF0000u); }

// truncated 3-plane split: v == top16(h)+top16(m)+top16(l) exactly (8+8+8 mantissa bits)
__device__ __forceinline__ void split3(float v, unsigned& h, unsigned& m, unsigned& l) {
    h = fbits(v);
    float r1 = v - topf(h);
    m = fbits(r1);
    float r2 = r1 - topf(m);
    l = fbits(r2);
}
// pack two bf16 (from fp32 bit patterns) into one dword: lo half = first (even k)
__device__ __forceinline__ unsigned packpair(unsigned a, unsigned b) {
    return (a >> 16) | (b & 0xFFFF0000u);
}
__device__ __forceinline__ bf16x8 as_bf(uint4 u) {
    union { uint4 a; bf16x8 b; } c; c.a = u; return c.b;
}

// non-draining workgroup barrier: completes LDS ops, leaves vmem loads in flight.
// (8-phase-template pattern, learn_hip m194-m201; sched_barrier guards per rule #18)
__device__ __forceinline__ void lds_barrier() {
    asm volatile("s_waitcnt lgkmcnt(0)" ::: "memory");
    __builtin_amdgcn_sched_barrier(0);
    __builtin_amdgcn_s_barrier();
    __builtin_amdgcn_sched_barrier(0);
}

// 8 consecutive-k floats -> three bf16x8 fragments (h/m/l planes) — gate phase only
__device__ __forceinline__ void split_pack8(float4 f0, float4 f1,
                                            bf16x8& H, bf16x8& M, bf16x8& L) {
    float v[8] = {f0.x, f0.y, f0.z, f0.w, f1.x, f1.y, f1.z, f1.w};
    unsigned hb[8], mb[8], lb[8];
#pragma unroll
    for (int j = 0; j < 8; j++) split3(v[j], hb[j], mb[j], lb[j]);
    uint4 uh = {packpair(hb[0], hb[1]), packpair(hb[2], hb[3]),
                packpair(hb[4], hb[5]), packpair(hb[6], hb[7])};
    uint4 um = {packpair(mb[0], mb[1]), packpair(mb[2], mb[3]),
                packpair(mb[4], mb[5]), packpair(mb[6], mb[7])};
    uint4 ul = {packpair(lb[0], lb[1]), packpair(lb[2], lb[3]),
                packpair(lb[4], lb[5]), packpair(lb[6], lb[7])};
    H = as_bf(uh); M = as_bf(um); L = as_bf(ul);
}

// Fragment conventions (empirically verified):
//   A-frag 16x16x32: m = lane&15, k = (lane>>4)*8 + j
//   B-frag:          n = lane&15, same k mapping
//   C/D:             col(n) = lane&15, row(m) = (lane>>4)*4 + reg

// ---------------- prep: weight planes in B-fragment order, LDS-tiled gather ----------------
__global__ __launch_bounds__(256)
void prep_planes(const float* __restrict__ W1, const float* __restrict__ W2,
                 char* __restrict__ ws) {
    __shared__ float tile[512];
    unsigned* w1p = (unsigned*)(ws + W1P_OFF);
    unsigned* w2p = (unsigned*)(ws + W2P_OFF);
    const int b = blockIdx.x, t = threadIdx.x;
    const int q = t & 3, L = (t >> 2) & 63;
    const int n_loc = L & 15;
    const int k_loc = ((L >> 4) & 3) * 8 + 2 * q;
    if (b < 512) {
        const int kc = b >> 4, nt = b & 15;
#pragma unroll
        for (int i = 0; i < 2; i++) {
            const int idx = t + i * 256;
            tile[idx] = W1[(size_t)(kc * 32 + (idx >> 4)) * DH + nt * 16 + (idx & 15)];
        }
        __syncthreads();
        const float v0 = tile[k_loc * 16 + n_loc];
        const float v1 = tile[(k_loc + 1) * 16 + n_loc];
        unsigned h0, m0, l0, h1, m1, l1;
        split3(v0, h0, m0, l0);
        split3(v1, h1, m1, l1);
        const int gt = b * 256 + t;
        w1p[0 * 131072 + gt] = packpair(h0, h1);
        w1p[1 * 131072 + gt] = packpair(m0, m1);
        w1p[2 * 131072 + gt] = packpair(l0, l1);
    } else {
        const int b2 = b - 512;
        const int kc = b2 >> 2, nt = b2 & 3;
#pragma unroll
        for (int i = 0; i < 2; i++) {
            const int idx = t + i * 256;
            tile[idx] = W2[(kc * 32 + (idx >> 4)) * NE + nt * 16 + (idx & 15)];
        }
        __syncthreads();
        const float v0 = tile[k_loc * 16 + n_loc];
        const float v1 = tile[(k_loc + 1) * 16 + n_loc];
        unsigned h0, m0, l0, h1, m1, l1;
        split3(v0, h0, m0, l0);
        split3(v1, h1, m1, l1);
        const int g2 = b2 * 256 + t;
        w2p[0 * 8192 + g2] = packpair(h0, h1);
        w2p[1 * 8192 + g2] = packpair(m0, m1);
        w2p[2 * 8192 + g2] = packpair(l0, l1);
    }
}

// ---------------- fused: h = tanh(x@W1+b1) ; logits = h@W2+b2 ; top-2 softmax ----------------
// 32 tokens/block, 512 threads = 8 waves, wave w covers hid [w*32, w*32+32).
// Per kc: A-frags from LDS (staged once, dbuf), B reg-prefetched depth-1 (L2),
// x reg-prefetched depth-3 (HBM). Non-draining barrier per kc.
__global__ __launch_bounds__(512, 4)
void fused_gating(const float* __restrict__ x, const char* __restrict__ w1p,
                  const float* __restrict__ b1, const char* __restrict__ w2p,
                  const float* __restrict__ b2, float* __restrict__ gates,
                  float* __restrict__ logits_out) {
    __shared__ __align__(16) char alds[2 * ABUF];     // 15360 B: A-plane double buffer
    __shared__ __align__(16) float hlds[32 * HSTR];   // 35328 B: h hand-off

    const int tid  = threadIdx.x;
    const int lane = tid & 63;
    const int wave = tid >> 6;        // hid slice [wave*32, wave*32+32)
    const int m15 = lane & 15;
    const int lq  = lane >> 4;
    const int t0 = blockIdx.x * 32;

    // staging role: thread -> (token stok, k-pair at skp); 512 threads = 32 tok x 16 pairs
    const int stok = tid >> 4;
    const int skp  = (tid & 15) * 2;
    const float* xs = x + (size_t)(t0 + stok) * DM + skp;
    const int swoff = stok * AROW + (tid & 15) * 4;

    // B frags: nt_global = wave*2 + nt (each of 16 nt covered exactly once)
    const char* bbase = w1p + (size_t)(wave * 2) * 1024 + lane * 16;

    f32x4 acc[2][2];
#pragma unroll
    for (int ms = 0; ms < 2; ms++)
#pragma unroll
        for (int nt = 0; nt < 2; nt++) acc[ms][nt] = (f32x4){0.f, 0.f, 0.f, 0.f};

    // prologue: B(0) into regs; stage kc=0 into buf0; x(1),x(2) into reg slots
    uint4 bc[3][2];
#pragma unroll
    for (int p = 0; p < 3; p++)
#pragma unroll
        for (int nt = 0; nt < 2; nt++)
            bc[p][nt] = *(const uint4*)(bbase + p * W1P_STRIDE + nt * 1024);
    {
        float2 v = *(const float2*)(xs);
        unsigned h0, m0, l0, h1, m1, l1;
        split3(v.x, h0, m0, l0);
        split3(v.y, h1, m1, l1);
        *(unsigned*)(alds + 0 * APLANE + swoff) = packpair(h0, h1);
        *(unsigned*)(alds + 1 * APLANE + swoff) = packpair(m0, m1);
        *(unsigned*)(alds + 2 * APLANE + swoff) = packpair(l0, l1);
    }
    float2 xc  = *(const float2*)(xs + 32);        // x(1): staged at kc=0
    float2 xc2 = *(const float2*)(xs + 64);        // x(2): staged at kc=1
    lds_barrier();

#pragma unroll 2
    for (int kc = 0; kc < 32; kc++) {
        // prefetch issue order matters: B FIRST, then x — the rotate's wait on bn
        // then lands at vmcnt(1), keeping the long-latency x load in flight.
        const int k1 = (kc + 1) & 31;
        const int k3 = (kc + 3) & 31;
        uint4 bn[3][2];
#pragma unroll
        for (int p = 0; p < 3; p++)
#pragma unroll
            for (int nt = 0; nt < 2; nt++)
                bn[p][nt] = *(const uint4*)(bbase + p * W1P_STRIDE + k1 * 16384 + nt * 1024);
        float2 xn = *(const float2*)(xs + k3 * 32);

        // A-frags from LDS current buffer
        const char* ab = alds + (kc & 1) * ABUF + m15 * AROW + lq * 16;
        const bf16x8 a0h = *(const bf16x8*)(ab + 0 * APLANE);
        const bf16x8 a0m = *(const bf16x8*)(ab + 1 * APLANE);
        const bf16x8 a0l = *(const bf16x8*)(ab + 2 * APLANE);
        const bf16x8 a1h = *(const bf16x8*)(ab + 0 * APLANE + 16 * AROW);
        const bf16x8 a1m = *(const bf16x8*)(ab + 1 * APLANE + 16 * AROW);
        const bf16x8 a1l = *(const bf16x8*)(ab + 2 * APLANE + 16 * AROW);

#pragma unroll
        for (int nt = 0; nt < 2; nt++) {
            const bf16x8 bh = as_bf(bc[0][nt]);
            const bf16x8 bm = as_bf(bc[1][nt]);
            const bf16x8 bl = as_bf(bc[2][nt]);
            f32x4 a0 = acc[0][nt];
            a0 = __builtin_amdgcn_mfma_f32_16x16x32_bf16(a0h, bh, a0, 0, 0, 0);
            a0 = __builtin_amdgcn_mfma_f32_16x16x32_bf16(a0h, bm, a0, 0, 0, 0);
            a0 = __builtin_amdgcn_mfma_f32_16x16x32_bf16(a0m, bh, a0, 0, 0, 0);
            a0 = __builtin_amdgcn_mfma_f32_16x16x32_bf16(a0h, bl, a0, 0, 0, 0);
            a0 = __builtin_amdgcn_mfma_f32_16x16x32_bf16(a0l, bh, a0, 0, 0, 0);
            a0 = __builtin_amdgcn_mfma_f32_16x16x32_bf16(a0m, bm, a0, 0, 0, 0);
            acc[0][nt] = a0;
            f32x4 a1 = acc[1][nt];
            a1 = __builtin_amdgcn_mfma_f32_16x16x32_bf16(a1h, bh, a1, 0, 0, 0);
            a1 = __builtin_amdgcn_mfma_f32_16x16x32_bf16(a1h, bm, a1, 0, 0, 0);
            a1 = __builtin_amdgcn_mfma_f32_16x16x32_bf16(a1m, bh, a1, 0, 0, 0);
            a1 = __builtin_amdgcn_mfma_f32_16x16x32_bf16(a1h, bl, a1, 0, 0, 0);
            a1 = __builtin_amdgcn_mfma_f32_16x16x32_bf16(a1l, bh, a1, 0, 0, 0);
            a1 = __builtin_amdgcn_mfma_f32_16x16x32_bf16(a1m, bm, a1, 0, 0, 0);
            acc[1][nt] = a1;
        }

        // stage kc+1 into other buffer from xc (loaded 3 iters ago — no vmem wait)
        {
            char* wb = alds + ((kc + 1) & 1) * ABUF + swoff;
            unsigned h0, m0, l0, h1, m1, l1;
            split3(xc.x, h0, m0, l0);
            split3(xc.y, h1, m1, l1);
            *(unsigned*)(wb + 0 * APLANE) = packpair(h0, h1);
            *(unsigned*)(wb + 1 * APLANE) = packpair(m0, m1);
            *(unsigned*)(wb + 2 * APLANE) = packpair(l0, l1);
        }
        xc = xc2; xc2 = xn;
#pragma unroll
        for (int p = 0; p < 3; p++)
#pragma unroll
            for (int nt = 0; nt < 2; nt++) bc[p][nt] = bn[p][nt];

        // non-draining barrier: LDS writes visible, vmem prefetches stay in flight
        lds_barrier();
    }

    // epilogue: bias + tanh -> h in LDS (C/D layout: col = m15, row = lq*4 + r)
#pragma unroll
    for (int nt = 0; nt < 2; nt++) {
        const int hid = wave * 32 + nt * 16 + m15;
        const float bias = b1[hid];
#pragma unroll
        for (int ms = 0; ms < 2; ms++) {
            const int tb = ms * 16 + lq * 4;
#pragma unroll
            for (int r = 0; r < 4; r++)
                hlds[(tb + r) * HSTR + hid] = tanhf(acc[ms][nt][r] + bias);
        }
    }
    __syncthreads();

    // ---- gate phase: waves 0-1, 16 tokens each, h from LDS ----
    if (wave < 2) {
        const float* hb = hlds + (wave * 16 + m15) * HSTR + lq * 8;
        const char* bt = w2p + lane * 16;

        f32x4 gacc[4];
#pragma unroll
        for (int nt = 0; nt < 4; nt++) gacc[nt] = (f32x4){0.f, 0.f, 0.f, 0.f};

#pragma unroll
        for (int kc = 0; kc < 8; kc++) {
            float4 f0 = *(const float4*)(hb + kc * 32);
            float4 f1 = *(const float4*)(hb + kc * 32 + 4);
            bf16x8 afh, afm, afl;
            split_pack8(f0, f1, afh, afm, afl);
#pragma unroll
            for (int nt = 0; nt < 4; nt++) {
                const char* tb = bt + (kc * 4 + nt) * 1024;
                bf16x8 bh = *(const bf16x8*)(tb + 0 * W2P_STRIDE);
                bf16x8 bm = *(const bf16x8*)(tb + 1 * W2P_STRIDE);
                bf16x8 bl = *(const bf16x8*)(tb + 2 * W2P_STRIDE);
                f32x4 a = gacc[nt];
                a = __builtin_amdgcn_mfma_f32_16x16x32_bf16(afh, bh, a, 0, 0, 0);
                a = __builtin_amdgcn_mfma_f32_16x16x32_bf16(afh, bm, a, 0, 0, 0);
                a = __builtin_amdgcn_mfma_f32_16x16x32_bf16(afm, bh, a, 0, 0, 0);
                a = __builtin_amdgcn_mfma_f32_16x16x32_bf16(afh, bl, a, 0, 0, 0);
                a = __builtin_amdgcn_mfma_f32_16x16x32_bf16(afl, bh, a, 0, 0, 0);
                a = __builtin_amdgcn_mfma_f32_16x16x32_bf16(afm, bm, a, 0, 0, 0);
                gacc[nt] = a;
            }
        }

        float b2v[4];
#pragma unroll
        for (int nt = 0; nt < 4; nt++) b2v[nt] = b2[nt * 16 + m15];

        // per r: lane holds 4 experts of token t0 + wave*16 + lq*4 + r
#pragma unroll
        for (int r = 0; r < 4; r++) {
            float v[4]; int e[4];
#pragma unroll
            for (int nt = 0; nt < 4; nt++) { v[nt] = gacc[nt][r] + b2v[nt]; e[nt] = nt * 16 + m15; }

            float a1 = v[0], a2 = v[1]; int j1 = e[0], j2 = e[1];
            if (v[1] > v[0]) { a1 = v[1]; j1 = e[1]; a2 = v[0]; j2 = e[0]; }
#pragma unroll
            for (int t = 2; t < 4; t++) {
                if (v[t] > a1) { a2 = a1; j2 = j1; a1 = v[t]; j1 = e[t]; }
                else if (v[t] > a2) { a2 = v[t]; j2 = e[t]; }
            }
#pragma unroll
            for (int off = 1; off < 16; off <<= 1) {
                float ob1 = __shfl_xor(a1, off, 64); int oj1 = __shfl_xor(j1, off, 64);
                float ob2 = __shfl_xor(a2, off, 64); int oj2 = __shfl_xor(j2, off, 64);
                bool bw = (ob1 > a1) || (ob1 == a1 && oj1 < j1);
                float w1v = bw ? ob1 : a1; int w1i = bw ? oj1 : j1;
                float lv = bw ? a1 : ob1;  int li  = bw ? j1 : oj1;   // loser of top duel
                float rv = bw ? ob2 : a2;  int ri  = bw ? oj2 : j2;   // winner side's runner-up
                bool cw = (lv > rv) || (lv == rv && li < ri);
                a1 = w1v; j1 = w1i;
                a2 = cw ? lv : rv; j2 = cw ? li : ri;
            }
            float ex = __expf(a2 - a1);            // a2 <= a1: stable
            float inv = 1.f / (1.f + ex);
            float g1 = inv, g2 = ex * inv;

            const size_t row = (size_t)(t0 + wave * 16 + lq * 4 + r) * NE;
#pragma unroll
            for (int nt = 0; nt < 4; nt++) {
                float gv = (e[nt] == j1) ? g1 : ((e[nt] == j2) ? g2 : 0.f);
                gates[row + e[nt]] = gv;
                logits_out[row + e[nt]] = v[nt];
            }
        }
    }
}

extern "C" void kernel_launch(void* const* d_in, const int* in_sizes, int n_in,
                              void* d_out, int out_size, void* d_ws, size_t ws_size,
                              hipStream_t stream) {
    const float* x  = (const float*)d_in[0];
    const float* W1 = (const float*)d_in[1];
    const float* b1 = (const float*)d_in[2];
    const float* W2 = (const float*)d_in[3];
    const float* b2 = (const float*)d_in[4];

    const int T = in_sizes[0] / DM;   // 16384
    char* ws = (char*)d_ws;
    float* gates  = (float*)d_out;
    float* logits = (float*)d_out + (size_t)T * NE;

    prep_planes<<<512 + 32, 256, 0, stream>>>(W1, W2, ws);
    fused_gating<<<T / 32, 512, 0, stream>>>(x, ws + W1P_OFF, b1, ws + W2P_OFF, b2,
                                             gates, logits);
}

// Round 7
// 149.317 us; speedup vs baseline: 1.0748x; 1.0748x over previous
//
#include <hip/hip_runtime.h>
#include <math.h>

// SegmentGatingNetwork, MFMA path v8: BK=64 K-loop (16 barriers instead of 32).
// v7 failed correctness from an off-by-one in the x-prefetch rotation: xn must
// load iter t+3 (invariant xc=t+1, xc2=t+2), not t+2 — v7 staged iter-2 data
// into the iter-3 slot and every later chunk was one behind. Fixed here.
// Per-iteration MFMA cluster = 48/wave so the fixed per-barrier overhead is
// paid half as often. Staging thread handles 4 consecutive k (float4 load,
// uint2 LDS writes x3 planes). No vmem carried across barriers. MFMA
// accumulation order identical to v5 (chunk0 then chunk1) -> bit-exact.

#define DM 1024
#define DH 256
#define NE 64

// d_ws layout (bytes)
#define W1P_OFF 0                 // 3 planes * 131072 dwords
#define W1P_STRIDE 524288         // bytes per W1 plane
#define W2P_OFF 1572864           // 3 planes * 8192 dwords
#define W2P_STRIDE 32768

#define HSTR 276                  // h LDS row stride in dwords
#define AROW 144                  // bytes per token row: 128 data + 16 pad (2-way banks max)
#define APLANE 4608               // 32 tokens * AROW
#define ABUF 13824                // 3 planes

typedef __attribute__((ext_vector_type(8))) short bf16x8;
typedef __attribute__((ext_vector_type(4))) float f32x4;

__device__ __forceinline__ unsigned fbits(float f) { return __float_as_uint(f); }
__device__ __forceinline__ float topf(unsigned u) { return __uint_as_float(u & 0xFFFF0000u); }

// truncated 3-plane split: v == top16(h)+top16(m)+top16(l) exactly (8+8+8 mantissa bits)
__device__ __forceinline__ void split3(float v, unsigned& h, unsigned& m, unsigned& l) {
    h = fbits(v);
    float r1 = v - topf(h);
    m = fbits(r1);
    float r2 = r1 - topf(m);
    l = fbits(r2);
}
// pack two bf16 (from fp32 bit patterns) into one dword: lo half = first (even k)
__device__ __forceinline__ unsigned packpair(unsigned a, unsigned b) {
    return (a >> 16) | (b & 0xFFFF0000u);
}
__device__ __forceinline__ bf16x8 as_bf(uint4 u) {
    union { uint4 a; bf16x8 b; } c; c.a = u; return c.b;
}

// stage 4 consecutive k of one token: float4 -> 2 packed dwords per plane, b64 writes
__device__ __forceinline__ void stage4(float4 f, char* wb) {
    unsigned h[4], m[4], l[4];
    split3(f.x, h[0], m[0], l[0]);
    split3(f.y, h[1], m[1], l[1]);
    split3(f.z, h[2], m[2], l[2]);
    split3(f.w, h[3], m[3], l[3]);
    uint2 dh = {packpair(h[0], h[1]), packpair(h[2], h[3])};
    uint2 dm = {packpair(m[0], m[1]), packpair(m[2], m[3])};
    uint2 dl = {packpair(l[0], l[1]), packpair(l[2], l[3])};
    *(uint2*)(wb + 0 * APLANE) = dh;
    *(uint2*)(wb + 1 * APLANE) = dm;
    *(uint2*)(wb + 2 * APLANE) = dl;
}

// 8 consecutive-k floats -> three bf16x8 fragments (h/m/l planes) — gate phase only
__device__ __forceinline__ void split_pack8(float4 f0, float4 f1,
                                            bf16x8& H, bf16x8& M, bf16x8& L) {
    float v[8] = {f0.x, f0.y, f0.z, f0.w, f1.x, f1.y, f1.z, f1.w};
    unsigned hb[8], mb[8], lb[8];
#pragma unroll
    for (int j = 0; j < 8; j++) split3(v[j], hb[j], mb[j], lb[j]);
    uint4 uh = {packpair(hb[0], hb[1]), packpair(hb[2], hb[3]),
                packpair(hb[4], hb[5]), packpair(hb[6], hb[7])};
    uint4 um = {packpair(mb[0], mb[1]), packpair(mb[2], mb[3]),
                packpair(mb[4], mb[5]), packpair(mb[6], mb[7])};
    uint4 ul = {packpair(lb[0], lb[1]), packpair(lb[2], lb[3]),
                packpair(lb[4], lb[5]), packpair(lb[6], lb[7])};
    H = as_bf(uh); M = as_bf(um); L = as_bf(ul);
}

// Fragment conventions (empirically verified):
//   A-frag 16x16x32: m = lane&15, k = (lane>>4)*8 + j
//   B-frag:          n = lane&15, same k mapping
//   C/D:             col(n) = lane&15, row(m) = (lane>>4)*4 + reg

// ---------------- prep: weight planes in B-fragment order, LDS-tiled gather ----------------
__global__ __launch_bounds__(256)
void prep_planes(const float* __restrict__ W1, const float* __restrict__ W2,
                 char* __restrict__ ws) {
    __shared__ float tile[512];
    unsigned* w1p = (unsigned*)(ws + W1P_OFF);
    unsigned* w2p = (unsigned*)(ws + W2P_OFF);
    const int b = blockIdx.x, t = threadIdx.x;
    const int q = t & 3, L = (t >> 2) & 63;
    const int n_loc = L & 15;
    const int k_loc = ((L >> 4) & 3) * 8 + 2 * q;
    if (b < 512) {
        const int kc = b >> 4, nt = b & 15;
#pragma unroll
        for (int i = 0; i < 2; i++) {
            const int idx = t + i * 256;
            tile[idx] = W1[(size_t)(kc * 32 + (idx >> 4)) * DH + nt * 16 + (idx & 15)];
        }
        __syncthreads();
        const float v0 = tile[k_loc * 16 + n_loc];
        const float v1 = tile[(k_loc + 1) * 16 + n_loc];
        unsigned h0, m0, l0, h1, m1, l1;
        split3(v0, h0, m0, l0);
        split3(v1, h1, m1, l1);
        const int gt = b * 256 + t;
        w1p[0 * 131072 + gt] = packpair(h0, h1);
        w1p[1 * 131072 + gt] = packpair(m0, m1);
        w1p[2 * 131072 + gt] = packpair(l0, l1);
    } else {
        const int b2 = b - 512;
        const int kc = b2 >> 2, nt = b2 & 3;
#pragma unroll
        for (int i = 0; i < 2; i++) {
            const int idx = t + i * 256;
            tile[idx] = W2[(kc * 32 + (idx >> 4)) * NE + nt * 16 + (idx & 15)];
        }
        __syncthreads();
        const float v0 = tile[k_loc * 16 + n_loc];
        const float v1 = tile[(k_loc + 1) * 16 + n_loc];
        unsigned h0, m0, l0, h1, m1, l1;
        split3(v0, h0, m0, l0);
        split3(v1, h1, m1, l1);
        const int g2 = b2 * 256 + t;
        w2p[0 * 8192 + g2] = packpair(h0, h1);
        w2p[1 * 8192 + g2] = packpair(m0, m1);
        w2p[2 * 8192 + g2] = packpair(l0, l1);
    }
}

// ---------------- fused: h = tanh(x@W1+b1) ; logits = h@W2+b2 ; top-2 softmax ----------------
// 32 tokens/block, 512 threads = 8 waves, wave w covers hid [w*32, w*32+32).
// BK=64: 16 iterations, each = 2 old k-chunks. A staged once per block in LDS (dbuf),
// B loaded per-iteration from L2 planes (no vmem carried across barriers).
__global__ __launch_bounds__(512, 4)
void fused_gating(const float* __restrict__ x, const char* __restrict__ w1p,
                  const float* __restrict__ b1, const char* __restrict__ w2p,
                  const float* __restrict__ b2, float* __restrict__ gates,
                  float* __restrict__ logits_out) {
    __shared__ __align__(16) char alds[2 * ABUF];     // 27648 B: A-plane double buffer
    __shared__ __align__(16) float hlds[32 * HSTR];   // 35328 B: h hand-off

    const int tid  = threadIdx.x;
    const int lane = tid & 63;
    const int wave = tid >> 6;        // hid slice [wave*32, wave*32+32)
    const int m15 = lane & 15;
    const int lq  = lane >> 4;
    const int t0 = blockIdx.x * 32;

    // staging role: thread -> (token stok, 4-k segment seg); 512 thr = 32 tok x 16 segs
    const int stok = tid >> 4;
    const int seg  = tid & 15;
    const float* xs = x + (size_t)(t0 + stok) * DM + seg * 4;
    const int swoff = stok * AROW + seg * 8;

    // B frags: nt_global = wave*2 + nt (each of 16 nt covered exactly once per block)
    const char* bbase = w1p + (size_t)(wave * 2) * 1024 + lane * 16;

    f32x4 acc[2][2];
#pragma unroll
    for (int ms = 0; ms < 2; ms++)
#pragma unroll
        for (int nt = 0; nt < 2; nt++) acc[ms][nt] = (f32x4){0.f, 0.f, 0.f, 0.f};

    // prologue: stage iter0 (k 0..63) into buf0; x(1),x(2) into reg slots
    stage4(*(const float4*)(xs), alds + swoff);
    float4 xc  = *(const float4*)(xs + 64);    // iter 1 data
    float4 xc2 = *(const float4*)(xs + 128);   // iter 2 data
    __syncthreads();

#pragma unroll 2
    for (int t = 0; t < 16; t++) {
        // B loads for both sub-chunks of this iteration (consumed in-iteration;
        // chunk1's use is ~400 cyc after issue -> L2 latency covered)
        const int kcA = 2 * t, kcB = 2 * t + 1;
        uint4 b0[3][2], b1f[3][2];
#pragma unroll
        for (int p = 0; p < 3; p++)
#pragma unroll
            for (int nt = 0; nt < 2; nt++) {
                b0[p][nt]  = *(const uint4*)(bbase + p * W1P_STRIDE + kcA * 16384 + nt * 1024);
                b1f[p][nt] = *(const uint4*)(bbase + p * W1P_STRIDE + kcB * 16384 + nt * 1024);
            }
        // x prefetch for iter t+3 (invariant: xc = t+1, xc2 = t+2, so the rotate
        // xc<-xc2, xc2<-xn needs xn = t+3; wrap on tail: in-bounds, value unused)
        float4 xn = *(const float4*)(xs + ((t + 3) & 15) * 64);

        const char* ab = alds + (t & 1) * ABUF + m15 * AROW + lq * 16;

        // ---- sub-chunk 0 (old kc = 2t) ----
        {
            const bf16x8 a0h = *(const bf16x8*)(ab + 0 * APLANE);
            const bf16x8 a0m = *(const bf16x8*)(ab + 1 * APLANE);
            const bf16x8 a0l = *(const bf16x8*)(ab + 2 * APLANE);
            const bf16x8 a1h = *(const bf16x8*)(ab + 0 * APLANE + 16 * AROW);
            const bf16x8 a1m = *(const bf16x8*)(ab + 1 * APLANE + 16 * AROW);
            const bf16x8 a1l = *(const bf16x8*)(ab + 2 * APLANE + 16 * AROW);
#pragma unroll
            for (int nt = 0; nt < 2; nt++) {
                const bf16x8 bh = as_bf(b0[0][nt]);
                const bf16x8 bm = as_bf(b0[1][nt]);
                const bf16x8 bl = as_bf(b0[2][nt]);
                f32x4 a0 = acc[0][nt];
                a0 = __builtin_amdgcn_mfma_f32_16x16x32_bf16(a0h, bh, a0, 0, 0, 0);
                a0 = __builtin_amdgcn_mfma_f32_16x16x32_bf16(a0h, bm, a0, 0, 0, 0);
                a0 = __builtin_amdgcn_mfma_f32_16x16x32_bf16(a0m, bh, a0, 0, 0, 0);
                a0 = __builtin_amdgcn_mfma_f32_16x16x32_bf16(a0h, bl, a0, 0, 0, 0);
                a0 = __builtin_amdgcn_mfma_f32_16x16x32_bf16(a0l, bh, a0, 0, 0, 0);
                a0 = __builtin_amdgcn_mfma_f32_16x16x32_bf16(a0m, bm, a0, 0, 0, 0);
                acc[0][nt] = a0;
                f32x4 a1 = acc[1][nt];
                a1 = __builtin_amdgcn_mfma_f32_16x16x32_bf16(a1h, bh, a1, 0, 0, 0);
                a1 = __builtin_amdgcn_mfma_f32_16x16x32_bf16(a1h, bm, a1, 0, 0, 0);
                a1 = __builtin_amdgcn_mfma_f32_16x16x32_bf16(a1m, bh, a1, 0, 0, 0);
                a1 = __builtin_amdgcn_mfma_f32_16x16x32_bf16(a1h, bl, a1, 0, 0, 0);
                a1 = __builtin_amdgcn_mfma_f32_16x16x32_bf16(a1l, bh, a1, 0, 0, 0);
                a1 = __builtin_amdgcn_mfma_f32_16x16x32_bf16(a1m, bm, a1, 0, 0, 0);
                acc[1][nt] = a1;
            }
        }
        // ---- sub-chunk 1 (old kc = 2t+1): +64 B within the row ----
        {
            const bf16x8 a0h = *(const bf16x8*)(ab + 0 * APLANE + 64);
            const bf16x8 a0m = *(const bf16x8*)(ab + 1 * APLANE + 64);
            const bf16x8 a0l = *(const bf16x8*)(ab + 2 * APLANE + 64);
            const bf16x8 a1h = *(const bf16x8*)(ab + 0 * APLANE + 16 * AROW + 64);
            const bf16x8 a1m = *(const bf16x8*)(ab + 1 * APLANE + 16 * AROW + 64);
            const bf16x8 a1l = *(const bf16x8*)(ab + 2 * APLANE + 16 * AROW + 64);
#pragma unroll
            for (int nt = 0; nt < 2; nt++) {
                const bf16x8 bh = as_bf(b1f[0][nt]);
                const bf16x8 bm = as_bf(b1f[1][nt]);
                const bf16x8 bl = as_bf(b1f[2][nt]);
                f32x4 a0 = acc[0][nt];
                a0 = __builtin_amdgcn_mfma_f32_16x16x32_bf16(a0h, bh, a0, 0, 0, 0);
                a0 = __builtin_amdgcn_mfma_f32_16x16x32_bf16(a0h, bm, a0, 0, 0, 0);
                a0 = __builtin_amdgcn_mfma_f32_16x16x32_bf16(a0m, bh, a0, 0, 0, 0);
                a0 = __builtin_amdgcn_mfma_f32_16x16x32_bf16(a0h, bl, a0, 0, 0, 0);
                a0 = __builtin_amdgcn_mfma_f32_16x16x32_bf16(a0l, bh, a0, 0, 0, 0);
                a0 = __builtin_amdgcn_mfma_f32_16x16x32_bf16(a0m, bm, a0, 0, 0, 0);
                acc[0][nt] = a0;
                f32x4 a1 = acc[1][nt];
                a1 = __builtin_amdgcn_mfma_f32_16x16x32_bf16(a1h, bh, a1, 0, 0, 0);
                a1 = __builtin_amdgcn_mfma_f32_16x16x32_bf16(a1h, bm, a1, 0, 0, 0);
                a1 = __builtin_amdgcn_mfma_f32_16x16x32_bf16(a1m, bh, a1, 0, 0, 0);
                a1 = __builtin_amdgcn_mfma_f32_16x16x32_bf16(a1h, bl, a1, 0, 0, 0);
                a1 = __builtin_amdgcn_mfma_f32_16x16x32_bf16(a1l, bh, a1, 0, 0, 0);
                a1 = __builtin_amdgcn_mfma_f32_16x16x32_bf16(a1m, bm, a1, 0, 0, 0);
                acc[1][nt] = a1;
            }
        }

        // stage iter t+1 into the other buffer (xc loaded >=2 iters ago — no vmem wait)
        stage4(xc, alds + ((t + 1) & 1) * ABUF + swoff);
        xc = xc2; xc2 = xn;
        __syncthreads();
    }

    // epilogue: bias + tanh -> h in LDS (C/D layout: col = m15, row = lq*4 + r)
#pragma unroll
    for (int nt = 0; nt < 2; nt++) {
        const int hid = wave * 32 + nt * 16 + m15;
        const float bias = b1[hid];
#pragma unroll
        for (int ms = 0; ms < 2; ms++) {
            const int tb = ms * 16 + lq * 4;
#pragma unroll
            for (int r = 0; r < 4; r++)
                hlds[(tb + r) * HSTR + hid] = tanhf(acc[ms][nt][r] + bias);
        }
    }
    __syncthreads();

    // ---- gate phase: waves 0-1, 16 tokens each, h from LDS ----
    if (wave < 2) {
        const float* hb = hlds + (wave * 16 + m15) * HSTR + lq * 8;
        const char* bt = w2p + lane * 16;

        f32x4 gacc[4];
#pragma unroll
        for (int nt = 0; nt < 4; nt++) gacc[nt] = (f32x4){0.f, 0.f, 0.f, 0.f};

#pragma unroll
        for (int kc = 0; kc < 8; kc++) {
            float4 f0 = *(const float4*)(hb + kc * 32);
            float4 f1 = *(const float4*)(hb + kc * 32 + 4);
            bf16x8 afh, afm, afl;
            split_pack8(f0, f1, afh, afm, afl);
#pragma unroll
            for (int nt = 0; nt < 4; nt++) {
                const char* tb = bt + (kc * 4 + nt) * 1024;
                bf16x8 bh = *(const bf16x8*)(tb + 0 * W2P_STRIDE);
                bf16x8 bm = *(const bf16x8*)(tb + 1 * W2P_STRIDE);
                bf16x8 bl = *(const bf16x8*)(tb + 2 * W2P_STRIDE);
                f32x4 a = gacc[nt];
                a = __builtin_amdgcn_mfma_f32_16x16x32_bf16(afh, bh, a, 0, 0, 0);
                a = __builtin_amdgcn_mfma_f32_16x16x32_bf16(afh, bm, a, 0, 0, 0);
                a = __builtin_amdgcn_mfma_f32_16x16x32_bf16(afm, bh, a, 0, 0, 0);
                a = __builtin_amdgcn_mfma_f32_16x16x32_bf16(afh, bl, a, 0, 0, 0);
                a = __builtin_amdgcn_mfma_f32_16x16x32_bf16(afl, bh, a, 0, 0, 0);
                a = __builtin_amdgcn_mfma_f32_16x16x32_bf16(afm, bm, a, 0, 0, 0);
                gacc[nt] = a;
            }
        }

        float b2v[4];
#pragma unroll
        for (int nt = 0; nt < 4; nt++) b2v[nt] = b2[nt * 16 + m15];

        // per r: lane holds 4 experts of token t0 + wave*16 + lq*4 + r
#pragma unroll
        for (int r = 0; r < 4; r++) {
            float v[4]; int e[4];
#pragma unroll
            for (int nt = 0; nt < 4; nt++) { v[nt] = gacc[nt][r] + b2v[nt]; e[nt] = nt * 16 + m15; }

            float a1 = v[0], a2 = v[1]; int j1 = e[0], j2 = e[1];
            if (v[1] > v[0]) { a1 = v[1]; j1 = e[1]; a2 = v[0]; j2 = e[0]; }
#pragma unroll
            for (int t = 2; t < 4; t++) {
                if (v[t] > a1) { a2 = a1; j2 = j1; a1 = v[t]; j1 = e[t]; }
                else if (v[t] > a2) { a2 = v[t]; j2 = e[t]; }
            }
#pragma unroll
            for (int off = 1; off < 16; off <<= 1) {
                float ob1 = __shfl_xor(a1, off, 64); int oj1 = __shfl_xor(j1, off, 64);
                float ob2 = __shfl_xor(a2, off, 64); int oj2 = __shfl_xor(j2, off, 64);
                bool bw = (ob1 > a1) || (ob1 == a1 && oj1 < j1);
                float w1v = bw ? ob1 : a1; int w1i = bw ? oj1 : j1;
                float lv = bw ? a1 : ob1;  int li  = bw ? j1 : oj1;   // loser of top duel
                float rv = bw ? ob2 : a2;  int ri  = bw ? oj2 : j2;   // winner side's runner-up
                bool cw = (lv > rv) || (lv == rv && li < ri);
                a1 = w1v; j1 = w1i;
                a2 = cw ? lv : rv; j2 = cw ? li : ri;
            }
            float ex = __expf(a2 - a1);            // a2 <= a1: stable
            float inv = 1.f / (1.f + ex);
            float g1 = inv, g2 = ex * inv;

            const size_t row = (size_t)(t0 + wave * 16 + lq * 4 + r) * NE;
#pragma unroll
            for (int nt = 0; nt < 4; nt++) {
                float gv = (e[nt] == j1) ? g1 : ((e[nt] == j2) ? g2 : 0.f);
                gates[row + e[nt]] = gv;
                logits_out[row + e[nt]] = v[nt];
            }
        }
    }
}

extern "C" void kernel_launch(void* const* d_in, const int* in_sizes, int n_in,
                              void* d_out, int out_size, void* d_ws, size_t ws_size,
                              hipStream_t stream) {
    const float* x  = (const float*)d_in[0];
    const float* W1 = (const float*)d_in[1];
    const float* b1 = (const float*)d_in[2];
    const float* W2 = (const float*)d_in[3];
    const float* b2 = (const float*)d_in[4];

    const int T = in_sizes[0] / DM;   // 16384
    char* ws = (char*)d_ws;
    float* gates  = (float*)d_out;
    float* logits = (float*)d_out + (size_t)T * NE;

    prep_planes<<<512 + 32, 256, 0, stream>>>(W1, W2, ws);
    fused_gating<<<T / 32, 512, 0, stream>>>(x, ws + W1P_OFF, b1, ws + W2P_OFF, b2,
                                             gates, logits);
}